// Round 4
// baseline (85.859 us; speedup 1.0000x reference)
//
#include <hip/hip_runtime.h>
#include <hip/hip_bf16.h>

#define N_ROWS 32768
#define K_DIM 512
#define OUT_DIM 512
#define N_TYPES 8
#define NB 520              // max 64-row blocks after per-type padding (512 + 8)

typedef __attribute__((ext_vector_type(8))) short bf16x8;
typedef __attribute__((ext_vector_type(4))) float f32x4;

__device__ inline ushort f2bf(float f) {
    __hip_bfloat16 h = __float2bfloat16(f);
    return *reinterpret_cast<ushort*>(&h);
}

// meta layout (ints): [0..7] counts, [8..16] padded bases pbase[0..8]
//                     (pbase[8]=meta[16]=padded total), [20..27] cursors
__global__ void k_init(int* meta) {
    if (threadIdx.x < 32) meta[threadIdx.x] = 0;
}

// per-block LDS histogram -> 8 global atomics per block
__global__ void k_hist(const int* __restrict__ x_type, int* meta) {
    __shared__ int cnt[N_TYPES];
    if (threadIdx.x < N_TYPES) cnt[threadIdx.x] = 0;
    __syncthreads();
    int i = blockIdx.x * 256 + threadIdx.x;
    atomicAdd(&cnt[x_type[i]], 1);
    __syncthreads();
    if (threadIdx.x < N_TYPES && cnt[threadIdx.x] > 0)
        atomicAdd(&meta[threadIdx.x], cnt[threadIdx.x]);
}

__global__ void k_scan(int* meta) {
    if (threadIdx.x == 0) {
        int s = 0;
        for (int t = 0; t < N_TYPES; ++t) {
            meta[8 + t]  = s;      // padded base
            meta[20 + t] = s;      // cursor
            s += (meta[t] + 63) & ~63;   // pad each type segment to 64
        }
        meta[16] = s;              // padded total
    }
}

// per-block LDS hist -> reserve range with 8 global atomics -> scatter
// (row_ids pre-filled with -1; pad slots stay -1)
__global__ void k_fill(const int* __restrict__ x_type, int* meta, int* __restrict__ row_ids) {
    __shared__ int lcnt[N_TYPES];
    __shared__ int lbase[N_TYPES];
    if (threadIdx.x < N_TYPES) lcnt[threadIdx.x] = 0;
    __syncthreads();
    int i = blockIdx.x * 256 + threadIdx.x;
    int t = x_type[i];
    int lpos = atomicAdd(&lcnt[t], 1);
    __syncthreads();
    if (threadIdx.x < N_TYPES)
        lbase[threadIdx.x] = (lcnt[threadIdx.x] > 0)
            ? atomicAdd(&meta[20 + threadIdx.x], lcnt[threadIdx.x]) : 0;
    __syncthreads();
    row_ids[lbase[t] + lpos] = i;
}

// W[t][k][c] fp32 -> Wt[t][c][k] bf16   (64x64 tiles through LDS)
__global__ void k_wt(const float* __restrict__ W, ushort* __restrict__ Wt) {
    __shared__ float tile[64][65];
    int t = blockIdx.x, kb = blockIdx.y, cb = blockIdx.z;
    const float* src = W + (size_t)t * K_DIM * OUT_DIM + (size_t)kb * 64 * OUT_DIM + cb * 64;
    #pragma unroll
    for (int j = 0; j < 16; ++j) {
        int idx = threadIdx.x + j * 256;
        int r = idx >> 6, c = idx & 63;
        tile[r][c] = src[(size_t)r * OUT_DIM + c];
    }
    __syncthreads();
    ushort* dst = Wt + (size_t)t * OUT_DIM * K_DIM + (size_t)(cb * 64) * K_DIM + kb * 64;
    #pragma unroll
    for (int j = 0; j < 16; ++j) {
        int idx = threadIdx.x + j * 256;
        int cc = idx >> 6, kk = idx & 63;
        dst[(size_t)cc * K_DIM + kk] = f2bf(tile[kk][cc]);
    }
}

// 64-row x full-512-col blocks; A-panel resident in LDS (XOR-swizzled),
// B fragments straight from global (Wt is L2-resident); barrier-free K-loop.
__global__ __launch_bounds__(512, 4) void k_gemm3(
    const float* __restrict__ x, const ushort* __restrict__ Wt,
    const int* __restrict__ meta, const int* __restrict__ row_ids,
    float* __restrict__ out) {

    __shared__ ushort As[64 * K_DIM];   // 64 KB; byte addr ^= (row&7)<<4
    __shared__ int rids[64];

    int b = blockIdx.x;
    int r0 = b * 64;
    if (r0 >= meta[16]) return;         // beyond padded total
    int type = 0;
    #pragma unroll
    for (int t = 0; t < N_TYPES; ++t)
        if (r0 >= meta[8 + t]) type = t;    // last t with pbase<=r0

    int tid = threadIdx.x;
    if (tid < 64) rids[tid] = row_ids[r0 + tid];
    __syncthreads();

    // ---- stage A panel: 64 rows x 512 k, fp32 -> bf16, swizzled LDS ----
    #pragma unroll
    for (int j = 0; j < 8; ++j) {
        int f = j * 512 + tid;          // 16B-chunk index
        int row = f >> 6, c8 = f & 63;  // c8: which 8-elem group in the row
        int rid = rids[row];
        ushort tmp[8] = {0, 0, 0, 0, 0, 0, 0, 0};
        if (rid >= 0) {
            const float* src = x + (size_t)rid * K_DIM + c8 * 8;
            float4 v0 = *reinterpret_cast<const float4*>(src);
            float4 v1 = *reinterpret_cast<const float4*>(src + 4);
            tmp[0] = f2bf(v0.x); tmp[1] = f2bf(v0.y); tmp[2] = f2bf(v0.z); tmp[3] = f2bf(v0.w);
            tmp[4] = f2bf(v1.x); tmp[5] = f2bf(v1.y); tmp[6] = f2bf(v1.z); tmp[7] = f2bf(v1.w);
        }
        int byte = (row * 1024 + c8 * 16) ^ ((row & 7) << 4);
        *reinterpret_cast<uint4*>((char*)As + byte) = *reinterpret_cast<const uint4*>(tmp);
    }
    __syncthreads();
    // ---- no more barriers: A is read-only from here ----

    const ushort* Wtt = Wt + (size_t)type * OUT_DIM * K_DIM;
    int wave = tid >> 6, lane = tid & 63;
    int wc = wave * 64;                 // wave owns output cols [wc, wc+64)
    int lrow = lane & 15;
    int lk8 = (lane >> 4) * 8;

    f32x4 acc[4][4] = {};

    #pragma unroll 2
    for (int kk = 0; kk < K_DIM; kk += 32) {
        bf16x8 af[4], bfr[4];
        #pragma unroll
        for (int ni = 0; ni < 4; ++ni)
            bfr[ni] = *reinterpret_cast<const bf16x8*>(
                Wtt + (size_t)(wc + ni * 16 + lrow) * K_DIM + kk + lk8);
        #pragma unroll
        for (int mi = 0; mi < 4; ++mi) {
            int row = mi * 16 + lrow;
            int byte = (row * 1024 + (kk + lk8) * 2) ^ ((row & 7) << 4);
            af[mi] = *reinterpret_cast<const bf16x8*>((const char*)As + byte);
        }
        #pragma unroll
        for (int mi = 0; mi < 4; ++mi)
            #pragma unroll
            for (int ni = 0; ni < 4; ++ni)
                acc[mi][ni] = __builtin_amdgcn_mfma_f32_16x16x32_bf16(af[mi], bfr[ni], acc[mi][ni], 0, 0, 0);
    }

    // epilogue: D row = (lane>>4)*4 + rr, col = lane&15
    int rgrp = (lane >> 4) * 4;
    #pragma unroll
    for (int mi = 0; mi < 4; ++mi) {
        #pragma unroll
        for (int rr = 0; rr < 4; ++rr) {
            int lr = mi * 16 + rgrp + rr;
            int gr = rids[lr];
            if (gr >= 0) {
                float* dst = out + (size_t)gr * OUT_DIM + wc;
                #pragma unroll
                for (int ni = 0; ni < 4; ++ni)
                    dst[ni * 16 + lrow] = acc[mi][ni][rr];
            }
        }
    }
}

extern "C" void kernel_launch(void* const* d_in, const int* in_sizes, int n_in,
                              void* d_out, int out_size, void* d_ws, size_t ws_size,
                              hipStream_t stream) {
    const float* x      = (const float*)d_in[0];
    const int*   x_type = (const int*)d_in[1];
    const float* W      = (const float*)d_in[2];
    float* out          = (float*)d_out;

    // workspace layout
    char* ws = (char*)d_ws;
    size_t off_rids = 256;
    size_t off_wt   = off_rids + sizeof(int) * (NB * 64);   // row_ids (padded)
    int* meta    = (int*)ws;
    int* row_ids = (int*)(ws + off_rids);
    ushort* Wt   = (ushort*)(ws + off_wt);                  // 4 MB bf16

    k_init<<<1, 64, 0, stream>>>(meta);
    k_hist<<<N_ROWS / 256, 256, 0, stream>>>(x_type, meta);
    k_scan<<<1, 64, 0, stream>>>(meta);
    hipMemsetAsync(row_ids, 0xFF, sizeof(int) * (NB * 64), stream);
    k_fill<<<N_ROWS / 256, 256, 0, stream>>>(x_type, meta, row_ids);

    dim3 wgrid(N_TYPES, K_DIM / 64, OUT_DIM / 64);
    k_wt<<<wgrid, 256, 0, stream>>>(W, Wt);

    k_gemm3<<<NB, 512, 0, stream>>>(x, Wt, meta, row_ids, out);
}